// Round 22
// baseline (203.471 us; speedup 1.0000x reference)
//
#include <hip/hip_runtime.h>
#include <hip/hip_bf16.h>

#define N2 16384
#define D  128
#define APANEL 65536                      // bytes per 256x128 bf16 A panel
#define BPANEL 32768                      // bytes per 128x128 bf16 B panel
#define SQC1 1.69864360258810896f         // sqrt(2*log2(e)), folded into zn
#define LN2  0.69314718055994530942f

typedef __bf16 bf16x8 __attribute__((ext_vector_type(8)));
typedef float  f32x4  __attribute__((ext_vector_type(4)));

#if __has_builtin(__builtin_amdgcn_exp2f)
#define EXP2(x) __builtin_amdgcn_exp2f(x)
#else
#define EXP2(x) exp2f(x)
#endif

__device__ __forceinline__ unsigned short f2bf(float f) {
    union { float f; unsigned u; } v; v.f = f;
    unsigned r = v.u + 0x7fffu + ((v.u >> 16) & 1u);
    return (unsigned short)(r >> 16);
}

// stage 256x128 A panel (64KB) -> ls0(rows 0-127) + ls1(rows 128-255).
// 512 threads x 8 x 16B. XOR swizzle on GLOBAL source (rule #21); reads use
// byte ^ ((rowl&7)<<4) within each 32KB half (8|128 so row&7 is half-local).
__device__ __forceinline__ void stage_A(const char* __restrict__ g,
                                        char* ls0, char* ls1, int tid) {
    const int wid = tid >> 6, lane = tid & 63;
    #pragma unroll
    for (int i = 0; i < 8; ++i) {
        int o = (wid << 13) + (i << 10) + (lane << 4);   // 0..65535
        int src = o ^ (((o >> 8) & 7) << 4);
        char* dst = (wid < 4) ? (ls0 + o) : (ls1 + (o - 32768));
        __builtin_amdgcn_global_load_lds(
            (const __attribute__((address_space(1))) unsigned*)(g + src),
            (__attribute__((address_space(3))) unsigned*)dst, 16, 0, 0);
    }
}

// stage 128x128 B panel (32KB): 512 threads x 4 x 16B, same swizzle scheme.
__device__ __forceinline__ void stage_B(const char* __restrict__ g,
                                        char* lds, int tid) {
    const int wid = tid >> 6, lane = tid & 63;
    #pragma unroll
    for (int i = 0; i < 4; ++i) {
        int o = (wid << 12) + (i << 10) + (lane << 4);   // 0..32767
        int src = o ^ (((o >> 8) & 7) << 4);
        __builtin_amdgcn_global_load_lds(
            (const __attribute__((address_space(1))) unsigned*)(g + src),
            (__attribute__((address_space(3))) unsigned*)(lds + o), 16, 0, 0);
    }
}

// ---------- kernel 1: L2-normalize -> bf16 sqrt(C1)*zn; pos-dot fp32 (R21) ----------
__global__ void k_norm(const float* __restrict__ z, unsigned short* __restrict__ zn,
                       float* __restrict__ rowsum, float* __restrict__ posparts,
                       float* __restrict__ out) {
    __shared__ float xs[4][64][2];
    __shared__ float ps[4];
    if (blockIdx.x < 64) rowsum[blockIdx.x * 256 + threadIdx.x] = 0.f;
    if (blockIdx.x == 64 && threadIdx.x == 0) out[0] = 0.f;
    int wid  = threadIdx.x >> 6, lane = threadIdx.x & 63;
    int row  = blockIdx.x * 4 + wid;
    const float2 v = ((const float2*)(z + (size_t)row * D))[lane];
    float ss = v.x * v.x + v.y * v.y;
    #pragma unroll
    for (int m = 1; m < 64; m <<= 1) ss += __shfl_xor(ss, m);
    float inv = SQC1 / fmaxf(sqrtf(ss), 1e-12f);
    float nx = v.x * inv, ny = v.y * inv;
    ushort2 o; o.x = f2bf(nx); o.y = f2bf(ny);
    ((ushort2*)(zn + (size_t)row * D))[lane] = o;

    xs[wid][lane][0] = nx; xs[wid][lane][1] = ny;
    __syncthreads();
    float d = nx * xs[wid ^ 1][lane][0] + ny * xs[wid ^ 1][lane][1];
    #pragma unroll
    for (int m = 1; m < 64; m <<= 1) d += __shfl_xor(d, m);
    if (lane == 0) ps[wid] = d;
    __syncthreads();
    if (threadIdx.x == 0)
        posparts[blockIdx.x] = ps[0] + ps[1] + ps[2] + ps[3];
}

// ---------- kernel 2: 256x128-tile symmetric sim GEMM (8 waves, R17 schedule) ----------
// stripe ti owns rows [256ti, 256ti+256) = blocks {2ti, 2ti+1}; visits
// jt=(2ti+s)&127, s in [0,65]. Specials (coverage verified over d=(y-x)&127):
//  s=0 : wr<2 diag-mask(li==lj), no cs | wr>=2 full rs+cs
//  s=1 : wr<2 skip                      | wr>=2 diag-mask(li==128+lj), no cs
//  s=64: wr<2 active iff ti<32          | wr>=2 full
//  s=65: wr<2 skip                      | wr>=2 active iff ti<32
// Chunks: c==0 -> s in {0..7,64,65} (nt=10, two half-tiles); c in [1,7] -> 8.
// Per-wave geometry/regs identical to the 52us R17 kernel (af[4][4], acc[4][4]).
__global__ __launch_bounds__(512, 4)
void k_sim(const unsigned short* __restrict__ zn, float* __restrict__ rowsum) {
    __shared__ unsigned short ls[2][BPANEL / 2];
    char* ls0 = (char*)&ls[0][0];
    char* ls1 = (char*)&ls[1][0];

    const int ti = blockIdx.y;            // 0..63
    const int c  = blockIdx.x;            // 0..7
    const int nt = (c == 0) ? 10 : 8;

    const int tid  = threadIdx.x;
    const int lane = tid & 63, wid = tid >> 6;
    const int wr = wid >> 1, wc = wid & 1;          // 4x2 waves: 64x64 each
    const int l16 = lane & 15, lg = lane >> 4;
    const char* znb = (const char*)zn;
    const f32x4 ZERO = {0.f, 0.f, 0.f, 0.f};

    // prologue: stage A(ti) both halves, pull per-wave A fragments to regs
    stage_A(znb + (size_t)ti * APANEL, ls0, ls1, tid);
    asm volatile("s_waitcnt vmcnt(0)" ::: "memory");
    __builtin_amdgcn_s_barrier();

    bf16x8 af[4][4];                                   // [kk][m]
    {
        char* abase = (wr < 2) ? ls0 : ls1;
        #pragma unroll
        for (int kk = 0; kk < 4; ++kk)
            #pragma unroll
            for (int m = 0; m < 4; ++m) {
                int rowl = ((wr & 1) * 64) + m * 16 + l16;   // row within half
                int d = rowl * 256 + kk * 64 + lg * 16;
                af[kk][m] = *(const bf16x8*)(abase + (d ^ ((rowl & 7) << 4)));
            }
    }
    asm volatile("s_waitcnt lgkmcnt(0)" ::: "memory");
    __builtin_amdgcn_s_barrier();                      // LDS free for B dbuf

    {   // first B panel
        int s0v = (c == 0) ? 0 : c * 8;
        stage_B(znb + (size_t)((2 * ti + s0v) & 127) * BPANEL, ls0, tid);
    }

    float rs[4][4];
    #pragma unroll
    for (int m = 0; m < 4; ++m)
        #pragma unroll
        for (int r = 0; r < 4; ++r) rs[m][r] = 0.f;

    for (int t = 0; t < nt; ++t) {
        const int s  = (c == 0 && t >= 8) ? (56 + t) : (c * 8 + t);
        const int jt = (2 * ti + s) & 127;
        char* rbuf = (t & 1) ? ls1 : ls0;
        char* sbuf = (t & 1) ? ls0 : ls1;
        if (t < nt - 1) {
            const int s1v = (c == 0 && t + 1 >= 8) ? (56 + t + 1) : (c * 8 + t + 1);
            stage_B(znb + (size_t)((2 * ti + s1v) & 127) * BPANEL, sbuf, tid);
            asm volatile("s_waitcnt vmcnt(4)" ::: "memory");  // B(t) landed
        } else {
            asm volatile("s_waitcnt vmcnt(0)" ::: "memory");
        }
        __builtin_amdgcn_s_barrier();

        bf16x8 bfr[4][4];                              // [kk][n]
        #pragma unroll
        for (int kk = 0; kk < 4; ++kk)
            #pragma unroll
            for (int n = 0; n < 4; ++n) {
                int row = wc * 64 + n * 16 + l16;      // B panel row (0..127)
                int d = row * 256 + kk * 64 + lg * 16;
                bfr[kk][n] = *(const bf16x8*)(rbuf + (d ^ ((row & 7) << 4)));
            }
        asm volatile("s_waitcnt lgkmcnt(0)" ::: "memory");
        __builtin_amdgcn_s_barrier();                  // rbuf free for next stage

        f32x4 acc[4][4];
        #pragma unroll
        for (int m = 0; m < 4; ++m)
            #pragma unroll
            for (int n = 0; n < 4; ++n)
                acc[m][n] = __builtin_amdgcn_mfma_f32_16x16x32_bf16(af[0][m], bfr[0][n], ZERO, 0, 0, 0);
        #pragma unroll
        for (int kk = 1; kk < 4; ++kk)
            #pragma unroll
            for (int m = 0; m < 4; ++m)
                #pragma unroll
                for (int n = 0; n < 4; ++n)
                    acc[m][n] = __builtin_amdgcn_mfma_f32_16x16x32_bf16(af[kk][m], bfr[kk][n], acc[m][n], 0, 0, 0);

        // per-wave flags (all wave-uniform)
        const bool low = (wr < 2);
        const bool s1f = (s == 1), s64f = (s == 64), s65f = (s == 65);
        bool active = low ? (!(s1f || s65f) && !(s64f && ti >= 32))
                          : (!(s65f && ti >= 32));
        const bool diag = (s == 0 && low) || (s1f && !low);
        const int dBase = s1f ? 128 : 0;

        if (active) {
            if (diag) {
                // diagonal sub-tile: mask self-sim, row sums only
                #pragma unroll
                for (int m = 0; m < 4; ++m)
                    #pragma unroll
                    for (int r = 0; r < 4; ++r) {
                        int li = wr * 64 + m * 16 + lg * 4 + r;
                        float a = 0.f;
                        #pragma unroll
                        for (int n = 0; n < 4; ++n) {
                            int lj = wc * 64 + n * 16 + l16;
                            float e = EXP2(acc[m][n][r]);
                            a += (li == dBase + lj) ? 0.f : e;
                        }
                        rs[m][r] += a;
                    }
            } else {
                float cs[4] = {0.f, 0.f, 0.f, 0.f};
                #pragma unroll
                for (int m = 0; m < 4; ++m)
                    #pragma unroll
                    for (int r = 0; r < 4; ++r) {
                        float a = 0.f;
                        #pragma unroll
                        for (int n = 0; n < 4; ++n) {
                            float e = EXP2(acc[m][n][r]);
                            a += e;
                            cs[n] += e;
                        }
                        rs[m][r] += a;
                    }
                // column flush: reduce over the 4 lg row-groups of this wave
                #pragma unroll
                for (int n = 0; n < 4; ++n) {
                    float v = cs[n];
                    v += __shfl_xor(v, 16);
                    v += __shfl_xor(v, 32);
                    if (lg == 0)
                        atomicAdd(&rowsum[jt * 128 + wc * 64 + n * 16 + l16], v);
                }
            }
        }
    }

    // row sums -> reduce across 16 column-lanes, one atomic/row
    #pragma unroll
    for (int m = 0; m < 4; ++m)
        #pragma unroll
        for (int r = 0; r < 4; ++r) {
            float v = rs[m][r];
            v += __shfl_xor(v, 1);
            v += __shfl_xor(v, 2);
            v += __shfl_xor(v, 4);
            v += __shfl_xor(v, 8);
            if (l16 == 0)
                atomicAdd(&rowsum[ti * 256 + wr * 64 + m * 16 + lg * 4 + r], v);
        }
}

// ---------- kernel 3: loss mean from rowsum + posparts (R21-verbatim) ----------
__global__ void k_loss_reduce(const float* __restrict__ rowsum,
                              const float* __restrict__ posparts,
                              float* __restrict__ out) {
    const int tid = threadIdx.x + blockIdx.x * 256;   // 64 blocks x 256 = 16384
    float part = logf(rowsum[tid]);
    if (blockIdx.x == 0) {
        float pp = 0.f;
        for (int i = threadIdx.x; i < N2 / 4; i += 256) pp += posparts[i];
        part -= LN2 * pp;
    }
    __shared__ float sm[4];
    #pragma unroll
    for (int m = 1; m < 64; m <<= 1) part += __shfl_xor(part, m);
    if ((threadIdx.x & 63) == 0) sm[threadIdx.x >> 6] = part;
    __syncthreads();
    if (threadIdx.x == 0)
        atomicAdd(out, (sm[0] + sm[1] + sm[2] + sm[3]) * (1.0f / (float)N2));
}

extern "C" void kernel_launch(void* const* d_in, const int* in_sizes, int n_in,
                              void* d_out, int out_size, void* d_ws, size_t ws_size,
                              hipStream_t stream) {
    const float* z = (const float*)d_in[0];
    float* out = (float*)d_out;

    unsigned short* zn = (unsigned short*)d_ws;                       // 4 MiB
    float* rowsum   = (float*)((char*)d_ws + (size_t)N2 * D * 2);     // 64 KiB
    float* posparts = rowsum + N2;                                    // 16 KiB

    k_norm<<<N2 / 4, 256, 0, stream>>>(z, zn, rowsum, posparts, out);
    dim3 grid(8, 64);                                                 // s-chunks x stripes
    k_sim<<<grid, 512, 0, stream>>>(zn, rowsum);
    k_loss_reduce<<<64, 256, 0, stream>>>(rowsum, posparts, out);
}

// Round 23
// 74.893 us; speedup vs baseline: 2.7168x; 2.7168x over previous
//
#include <hip/hip_runtime.h>
#include <hip/hip_bf16.h>

#define N2 16384
#define D  128
#define APANEL 65536                      // bytes per 256x128 bf16 A panel
#define BPANEL 32768                      // bytes per 128x128 bf16 B panel
#define SQC1 1.69864360258810896f         // sqrt(2*log2(e)), folded into zn
#define LN2  0.69314718055994530942f

typedef __bf16 bf16x8 __attribute__((ext_vector_type(8)));
typedef float  f32x4  __attribute__((ext_vector_type(4)));

#if __has_builtin(__builtin_amdgcn_exp2f)
#define EXP2(x) __builtin_amdgcn_exp2f(x)
#else
#define EXP2(x) exp2f(x)
#endif

__device__ __forceinline__ unsigned short f2bf(float f) {
    union { float f; unsigned u; } v; v.f = f;
    unsigned r = v.u + 0x7fffu + ((v.u >> 16) & 1u);
    return (unsigned short)(r >> 16);
}

// stage 256x128 A panel (64KB) -> ls0(rows 0-127) + ls1(rows 128-255).
// 512 threads x 8 x 16B. XOR swizzle on GLOBAL source (rule #21); reads use
// byte ^ ((rowl&7)<<4) within each 32KB half (8|128 so row&7 is half-local).
__device__ __forceinline__ void stage_A(const char* __restrict__ g,
                                        char* ls0, char* ls1, int tid) {
    const int wid = tid >> 6, lane = tid & 63;
    #pragma unroll
    for (int i = 0; i < 8; ++i) {
        int o = (wid << 13) + (i << 10) + (lane << 4);   // 0..65535
        int src = o ^ (((o >> 8) & 7) << 4);
        char* dst = (wid < 4) ? (ls0 + o) : (ls1 + (o - 32768));
        __builtin_amdgcn_global_load_lds(
            (const __attribute__((address_space(1))) unsigned*)(g + src),
            (__attribute__((address_space(3))) unsigned*)dst, 16, 0, 0);
    }
}

// stage 128x128 B panel (32KB): 512 threads x 4 x 16B, same swizzle scheme.
__device__ __forceinline__ void stage_B(const char* __restrict__ g,
                                        char* lds, int tid) {
    const int wid = tid >> 6, lane = tid & 63;
    #pragma unroll
    for (int i = 0; i < 4; ++i) {
        int o = (wid << 12) + (i << 10) + (lane << 4);   // 0..32767
        int src = o ^ (((o >> 8) & 7) << 4);
        __builtin_amdgcn_global_load_lds(
            (const __attribute__((address_space(1))) unsigned*)(g + src),
            (__attribute__((address_space(3))) unsigned*)(lds + o), 16, 0, 0);
    }
}

// ---------- kernel 1: L2-normalize -> bf16 sqrt(C1)*zn; pos-dot fp32 (R21) ----------
__global__ void k_norm(const float* __restrict__ z, unsigned short* __restrict__ zn,
                       float* __restrict__ rowsum, float* __restrict__ posparts,
                       float* __restrict__ out) {
    __shared__ float xs[4][64][2];
    __shared__ float ps[4];
    if (blockIdx.x < 64) rowsum[blockIdx.x * 256 + threadIdx.x] = 0.f;
    if (blockIdx.x == 64 && threadIdx.x == 0) out[0] = 0.f;
    int wid  = threadIdx.x >> 6, lane = threadIdx.x & 63;
    int row  = blockIdx.x * 4 + wid;
    const float2 v = ((const float2*)(z + (size_t)row * D))[lane];
    float ss = v.x * v.x + v.y * v.y;
    #pragma unroll
    for (int m = 1; m < 64; m <<= 1) ss += __shfl_xor(ss, m);
    float inv = SQC1 / fmaxf(sqrtf(ss), 1e-12f);
    float nx = v.x * inv, ny = v.y * inv;
    ushort2 o; o.x = f2bf(nx); o.y = f2bf(ny);
    ((ushort2*)(zn + (size_t)row * D))[lane] = o;

    xs[wid][lane][0] = nx; xs[wid][lane][1] = ny;
    __syncthreads();
    float d = nx * xs[wid ^ 1][lane][0] + ny * xs[wid ^ 1][lane][1];
    #pragma unroll
    for (int m = 1; m < 64; m <<= 1) d += __shfl_xor(d, m);
    if (lane == 0) ps[wid] = d;
    __syncthreads();
    if (threadIdx.x == 0)
        posparts[blockIdx.x] = ps[0] + ps[1] + ps[2] + ps[3];
}

// ---------- kernel 2: 256x128-tile symmetric sim GEMM (8 waves, R17 schedule) ----------
// IDENTICAL to R22 except __launch_bounds__(512,2): 256 regs/wave cap fits
// the ~184-reg wave (R22's (512,4) capped at 128 -> total spill, 416MB FETCH).
// stripe ti owns rows [256ti, 256ti+256); visits jt=(2ti+s)&127, s in [0,65].
// Specials: s=0: low diag-mask/no-cs, high full | s=1: low skip, high
// diag-mask(li==128+lj)/no-cs | s=64: low iff ti<32 | s=65: low skip, high
// iff ti<32. Chunks: c==0 -> {0..7,64,65}; c in [1,7] -> 8 each.
__global__ __launch_bounds__(512, 2)
void k_sim(const unsigned short* __restrict__ zn, float* __restrict__ rowsum) {
    __shared__ unsigned short ls[2][BPANEL / 2];
    char* ls0 = (char*)&ls[0][0];
    char* ls1 = (char*)&ls[1][0];

    const int ti = blockIdx.y;            // 0..63
    const int c  = blockIdx.x;            // 0..7
    const int nt = (c == 0) ? 10 : 8;

    const int tid  = threadIdx.x;
    const int lane = tid & 63, wid = tid >> 6;
    const int wr = wid >> 1, wc = wid & 1;          // 4x2 waves: 64x64 each
    const int l16 = lane & 15, lg = lane >> 4;
    const char* znb = (const char*)zn;
    const f32x4 ZERO = {0.f, 0.f, 0.f, 0.f};

    // prologue: stage A(ti) both halves, pull per-wave A fragments to regs
    stage_A(znb + (size_t)ti * APANEL, ls0, ls1, tid);
    asm volatile("s_waitcnt vmcnt(0)" ::: "memory");
    __builtin_amdgcn_s_barrier();

    bf16x8 af[4][4];                                   // [kk][m]
    {
        char* abase = (wr < 2) ? ls0 : ls1;
        #pragma unroll
        for (int kk = 0; kk < 4; ++kk)
            #pragma unroll
            for (int m = 0; m < 4; ++m) {
                int rowl = ((wr & 1) * 64) + m * 16 + l16;   // row within half
                int d = rowl * 256 + kk * 64 + lg * 16;
                af[kk][m] = *(const bf16x8*)(abase + (d ^ ((rowl & 7) << 4)));
            }
    }
    asm volatile("s_waitcnt lgkmcnt(0)" ::: "memory");
    __builtin_amdgcn_s_barrier();                      // LDS free for B dbuf

    {   // first B panel
        int s0v = (c == 0) ? 0 : c * 8;
        stage_B(znb + (size_t)((2 * ti + s0v) & 127) * BPANEL, ls0, tid);
    }

    float rs[4][4];
    #pragma unroll
    for (int m = 0; m < 4; ++m)
        #pragma unroll
        for (int r = 0; r < 4; ++r) rs[m][r] = 0.f;

    for (int t = 0; t < nt; ++t) {
        const int s  = (c == 0 && t >= 8) ? (56 + t) : (c * 8 + t);
        const int jt = (2 * ti + s) & 127;
        char* rbuf = (t & 1) ? ls1 : ls0;
        char* sbuf = (t & 1) ? ls0 : ls1;
        if (t < nt - 1) {
            const int s1v = (c == 0 && t + 1 >= 8) ? (56 + t + 1) : (c * 8 + t + 1);
            stage_B(znb + (size_t)((2 * ti + s1v) & 127) * BPANEL, sbuf, tid);
            asm volatile("s_waitcnt vmcnt(4)" ::: "memory");  // B(t) landed
        } else {
            asm volatile("s_waitcnt vmcnt(0)" ::: "memory");
        }
        __builtin_amdgcn_s_barrier();

        bf16x8 bfr[4][4];                              // [kk][n]
        #pragma unroll
        for (int kk = 0; kk < 4; ++kk)
            #pragma unroll
            for (int n = 0; n < 4; ++n) {
                int row = wc * 64 + n * 16 + l16;      // B panel row (0..127)
                int d = row * 256 + kk * 64 + lg * 16;
                bfr[kk][n] = *(const bf16x8*)(rbuf + (d ^ ((row & 7) << 4)));
            }
        asm volatile("s_waitcnt lgkmcnt(0)" ::: "memory");
        __builtin_amdgcn_s_barrier();                  // rbuf free for next stage

        f32x4 acc[4][4];
        #pragma unroll
        for (int m = 0; m < 4; ++m)
            #pragma unroll
            for (int n = 0; n < 4; ++n)
                acc[m][n] = __builtin_amdgcn_mfma_f32_16x16x32_bf16(af[0][m], bfr[0][n], ZERO, 0, 0, 0);
        #pragma unroll
        for (int kk = 1; kk < 4; ++kk)
            #pragma unroll
            for (int m = 0; m < 4; ++m)
                #pragma unroll
                for (int n = 0; n < 4; ++n)
                    acc[m][n] = __builtin_amdgcn_mfma_f32_16x16x32_bf16(af[kk][m], bfr[kk][n], acc[m][n], 0, 0, 0);

        // per-wave flags (all wave-uniform)
        const bool low = (wr < 2);
        const bool s1f = (s == 1), s64f = (s == 64), s65f = (s == 65);
        bool active = low ? (!(s1f || s65f) && !(s64f && ti >= 32))
                          : (!(s65f && ti >= 32));
        const bool diag = (s == 0 && low) || (s1f && !low);
        const int dBase = s1f ? 128 : 0;

        if (active) {
            if (diag) {
                // diagonal sub-tile: mask self-sim, row sums only
                #pragma unroll
                for (int m = 0; m < 4; ++m)
                    #pragma unroll
                    for (int r = 0; r < 4; ++r) {
                        int li = wr * 64 + m * 16 + lg * 4 + r;
                        float a = 0.f;
                        #pragma unroll
                        for (int n = 0; n < 4; ++n) {
                            int lj = wc * 64 + n * 16 + l16;
                            float e = EXP2(acc[m][n][r]);
                            a += (li == dBase + lj) ? 0.f : e;
                        }
                        rs[m][r] += a;
                    }
            } else {
                float cs[4] = {0.f, 0.f, 0.f, 0.f};
                #pragma unroll
                for (int m = 0; m < 4; ++m)
                    #pragma unroll
                    for (int r = 0; r < 4; ++r) {
                        float a = 0.f;
                        #pragma unroll
                        for (int n = 0; n < 4; ++n) {
                            float e = EXP2(acc[m][n][r]);
                            a += e;
                            cs[n] += e;
                        }
                        rs[m][r] += a;
                    }
                // column flush: reduce over the 4 lg row-groups of this wave
                #pragma unroll
                for (int n = 0; n < 4; ++n) {
                    float v = cs[n];
                    v += __shfl_xor(v, 16);
                    v += __shfl_xor(v, 32);
                    if (lg == 0)
                        atomicAdd(&rowsum[jt * 128 + wc * 64 + n * 16 + l16], v);
                }
            }
        }
    }

    // row sums -> reduce across 16 column-lanes, one atomic/row
    #pragma unroll
    for (int m = 0; m < 4; ++m)
        #pragma unroll
        for (int r = 0; r < 4; ++r) {
            float v = rs[m][r];
            v += __shfl_xor(v, 1);
            v += __shfl_xor(v, 2);
            v += __shfl_xor(v, 4);
            v += __shfl_xor(v, 8);
            if (l16 == 0)
                atomicAdd(&rowsum[ti * 256 + wr * 64 + m * 16 + lg * 4 + r], v);
        }
}

// ---------- kernel 3: loss mean from rowsum + posparts (R21-verbatim) ----------
__global__ void k_loss_reduce(const float* __restrict__ rowsum,
                              const float* __restrict__ posparts,
                              float* __restrict__ out) {
    const int tid = threadIdx.x + blockIdx.x * 256;   // 64 blocks x 256 = 16384
    float part = logf(rowsum[tid]);
    if (blockIdx.x == 0) {
        float pp = 0.f;
        for (int i = threadIdx.x; i < N2 / 4; i += 256) pp += posparts[i];
        part -= LN2 * pp;
    }
    __shared__ float sm[4];
    #pragma unroll
    for (int m = 1; m < 64; m <<= 1) part += __shfl_xor(part, m);
    if ((threadIdx.x & 63) == 0) sm[threadIdx.x >> 6] = part;
    __syncthreads();
    if (threadIdx.x == 0)
        atomicAdd(out, (sm[0] + sm[1] + sm[2] + sm[3]) * (1.0f / (float)N2));
}

extern "C" void kernel_launch(void* const* d_in, const int* in_sizes, int n_in,
                              void* d_out, int out_size, void* d_ws, size_t ws_size,
                              hipStream_t stream) {
    const float* z = (const float*)d_in[0];
    float* out = (float*)d_out;

    unsigned short* zn = (unsigned short*)d_ws;                       // 4 MiB
    float* rowsum   = (float*)((char*)d_ws + (size_t)N2 * D * 2);     // 64 KiB
    float* posparts = rowsum + N2;                                    // 16 KiB

    k_norm<<<N2 / 4, 256, 0, stream>>>(z, zn, rowsum, posparts, out);
    dim3 grid(8, 64);                                                 // s-chunks x stripes
    k_sim<<<grid, 512, 0, stream>>>(zn, rowsum);
    k_loss_reduce<<<64, 256, 0, stream>>>(rowsum, posparts, out);
}

// Round 24
// 74.842 us; speedup vs baseline: 2.7187x; 1.0007x over previous
//
#include <hip/hip_runtime.h>
#include <hip/hip_bf16.h>

#define N2 16384
#define D  128
#define APANEL 65536                      // bytes per 256x128 bf16 A panel
#define BPANEL 32768                      // bytes per 128x128 bf16 B panel
#define SQC1 1.69864360258810896f         // sqrt(2*log2(e)), folded into zn
#define LN2  0.69314718055994530942f

typedef __bf16 bf16x8 __attribute__((ext_vector_type(8)));
typedef float  f32x4  __attribute__((ext_vector_type(4)));

#if __has_builtin(__builtin_amdgcn_exp2f)
#define EXP2(x) __builtin_amdgcn_exp2f(x)
#else
#define EXP2(x) exp2f(x)
#endif

__device__ __forceinline__ unsigned short f2bf(float f) {
    union { float f; unsigned u; } v; v.f = f;
    unsigned r = v.u + 0x7fffu + ((v.u >> 16) & 1u);
    return (unsigned short)(r >> 16);
}

// stage 256x128 A panel (64KB) -> ls0(rows 0-127) + ls1(rows 128-255).
// 512 threads x 8 x 16B. XOR swizzle on GLOBAL source (rule #21); reads use
// byte ^ ((rowl&7)<<4) within each 32KB half (8|128 so row&7 is half-local).
__device__ __forceinline__ void stage_A(const char* __restrict__ g,
                                        char* ls0, char* ls1, int tid) {
    const int wid = tid >> 6, lane = tid & 63;
    #pragma unroll
    for (int i = 0; i < 8; ++i) {
        int o = (wid << 13) + (i << 10) + (lane << 4);   // 0..65535
        int src = o ^ (((o >> 8) & 7) << 4);
        char* dst = (wid < 4) ? (ls0 + o) : (ls1 + (o - 32768));
        __builtin_amdgcn_global_load_lds(
            (const __attribute__((address_space(1))) unsigned*)(g + src),
            (__attribute__((address_space(3))) unsigned*)dst, 16, 0, 0);
    }
}

// stage 128x128 B panel (32KB): 512 threads x 4 x 16B, same swizzle scheme.
__device__ __forceinline__ void stage_B(const char* __restrict__ g,
                                        char* lds, int tid) {
    const int wid = tid >> 6, lane = tid & 63;
    #pragma unroll
    for (int i = 0; i < 4; ++i) {
        int o = (wid << 12) + (i << 10) + (lane << 4);   // 0..32767
        int src = o ^ (((o >> 8) & 7) << 4);
        __builtin_amdgcn_global_load_lds(
            (const __attribute__((address_space(1))) unsigned*)(g + src),
            (__attribute__((address_space(3))) unsigned*)(lds + o), 16, 0, 0);
    }
}

// ---------- kernel 1: L2-normalize -> bf16 sqrt(C1)*zn; pos-dot fp32 (R21) ----------
__global__ void k_norm(const float* __restrict__ z, unsigned short* __restrict__ zn,
                       float* __restrict__ rowsum, float* __restrict__ posparts,
                       float* __restrict__ out) {
    __shared__ float xs[4][64][2];
    __shared__ float ps[4];
    if (blockIdx.x < 64) rowsum[blockIdx.x * 256 + threadIdx.x] = 0.f;
    if (blockIdx.x == 64 && threadIdx.x == 0) out[0] = 0.f;
    int wid  = threadIdx.x >> 6, lane = threadIdx.x & 63;
    int row  = blockIdx.x * 4 + wid;
    const float2 v = ((const float2*)(z + (size_t)row * D))[lane];
    float ss = v.x * v.x + v.y * v.y;
    #pragma unroll
    for (int m = 1; m < 64; m <<= 1) ss += __shfl_xor(ss, m);
    float inv = SQC1 / fmaxf(sqrtf(ss), 1e-12f);
    float nx = v.x * inv, ny = v.y * inv;
    ushort2 o; o.x = f2bf(nx); o.y = f2bf(ny);
    ((ushort2*)(zn + (size_t)row * D))[lane] = o;

    xs[wid][lane][0] = nx; xs[wid][lane][1] = ny;
    __syncthreads();
    float d = nx * xs[wid ^ 1][lane][0] + ny * xs[wid ^ 1][lane][1];
    #pragma unroll
    for (int m = 1; m < 64; m <<= 1) d += __shfl_xor(d, m);
    if (lane == 0) ps[wid] = d;
    __syncthreads();
    if (threadIdx.x == 0)
        posparts[blockIdx.x] = ps[0] + ps[1] + ps[2] + ps[3];
}

// ---------- kernel 2: 256x128-tile symmetric sim GEMM (8 waves, R17 schedule) ----------
// IDENTICAL to R22 except __launch_bounds__(512,2): 256 regs/wave cap fits
// the ~184-reg wave (R22's (512,4) capped at 128 -> total spill, 416MB FETCH).
// stripe ti owns rows [256ti, 256ti+256); visits jt=(2ti+s)&127, s in [0,65].
// Specials: s=0: low diag-mask/no-cs, high full | s=1: low skip, high
// diag-mask(li==128+lj)/no-cs | s=64: low iff ti<32 | s=65: low skip, high
// iff ti<32. Chunks: c==0 -> {0..7,64,65}; c in [1,7] -> 8 each.
__global__ __launch_bounds__(512, 2)
void k_sim(const unsigned short* __restrict__ zn, float* __restrict__ rowsum) {
    __shared__ unsigned short ls[2][BPANEL / 2];
    char* ls0 = (char*)&ls[0][0];
    char* ls1 = (char*)&ls[1][0];

    const int ti = blockIdx.y;            // 0..63
    const int c  = blockIdx.x;            // 0..7
    const int nt = (c == 0) ? 10 : 8;

    const int tid  = threadIdx.x;
    const int lane = tid & 63, wid = tid >> 6;
    const int wr = wid >> 1, wc = wid & 1;          // 4x2 waves: 64x64 each
    const int l16 = lane & 15, lg = lane >> 4;
    const char* znb = (const char*)zn;
    const f32x4 ZERO = {0.f, 0.f, 0.f, 0.f};

    // prologue: stage A(ti) both halves, pull per-wave A fragments to regs
    stage_A(znb + (size_t)ti * APANEL, ls0, ls1, tid);
    asm volatile("s_waitcnt vmcnt(0)" ::: "memory");
    __builtin_amdgcn_s_barrier();

    bf16x8 af[4][4];                                   // [kk][m]
    {
        char* abase = (wr < 2) ? ls0 : ls1;
        #pragma unroll
        for (int kk = 0; kk < 4; ++kk)
            #pragma unroll
            for (int m = 0; m < 4; ++m) {
                int rowl = ((wr & 1) * 64) + m * 16 + l16;   // row within half
                int d = rowl * 256 + kk * 64 + lg * 16;
                af[kk][m] = *(const bf16x8*)(abase + (d ^ ((rowl & 7) << 4)));
            }
    }
    asm volatile("s_waitcnt lgkmcnt(0)" ::: "memory");
    __builtin_amdgcn_s_barrier();                      // LDS free for B dbuf

    {   // first B panel
        int s0v = (c == 0) ? 0 : c * 8;
        stage_B(znb + (size_t)((2 * ti + s0v) & 127) * BPANEL, ls0, tid);
    }

    float rs[4][4];
    #pragma unroll
    for (int m = 0; m < 4; ++m)
        #pragma unroll
        for (int r = 0; r < 4; ++r) rs[m][r] = 0.f;

    for (int t = 0; t < nt; ++t) {
        const int s  = (c == 0 && t >= 8) ? (56 + t) : (c * 8 + t);
        const int jt = (2 * ti + s) & 127;
        char* rbuf = (t & 1) ? ls1 : ls0;
        char* sbuf = (t & 1) ? ls0 : ls1;
        if (t < nt - 1) {
            const int s1v = (c == 0 && t + 1 >= 8) ? (56 + t + 1) : (c * 8 + t + 1);
            stage_B(znb + (size_t)((2 * ti + s1v) & 127) * BPANEL, sbuf, tid);
            asm volatile("s_waitcnt vmcnt(4)" ::: "memory");  // B(t) landed
        } else {
            asm volatile("s_waitcnt vmcnt(0)" ::: "memory");
        }
        __builtin_amdgcn_s_barrier();

        bf16x8 bfr[4][4];                              // [kk][n]
        #pragma unroll
        for (int kk = 0; kk < 4; ++kk)
            #pragma unroll
            for (int n = 0; n < 4; ++n) {
                int row = wc * 64 + n * 16 + l16;      // B panel row (0..127)
                int d = row * 256 + kk * 64 + lg * 16;
                bfr[kk][n] = *(const bf16x8*)(rbuf + (d ^ ((row & 7) << 4)));
            }
        asm volatile("s_waitcnt lgkmcnt(0)" ::: "memory");
        __builtin_amdgcn_s_barrier();                  // rbuf free for next stage

        f32x4 acc[4][4];
        #pragma unroll
        for (int m = 0; m < 4; ++m)
            #pragma unroll
            for (int n = 0; n < 4; ++n)
                acc[m][n] = __builtin_amdgcn_mfma_f32_16x16x32_bf16(af[0][m], bfr[0][n], ZERO, 0, 0, 0);
        #pragma unroll
        for (int kk = 1; kk < 4; ++kk)
            #pragma unroll
            for (int m = 0; m < 4; ++m)
                #pragma unroll
                for (int n = 0; n < 4; ++n)
                    acc[m][n] = __builtin_amdgcn_mfma_f32_16x16x32_bf16(af[kk][m], bfr[kk][n], acc[m][n], 0, 0, 0);

        // per-wave flags (all wave-uniform)
        const bool low = (wr < 2);
        const bool s1f = (s == 1), s64f = (s == 64), s65f = (s == 65);
        bool active = low ? (!(s1f || s65f) && !(s64f && ti >= 32))
                          : (!(s65f && ti >= 32));
        const bool diag = (s == 0 && low) || (s1f && !low);
        const int dBase = s1f ? 128 : 0;

        if (active) {
            if (diag) {
                // diagonal sub-tile: mask self-sim, row sums only
                #pragma unroll
                for (int m = 0; m < 4; ++m)
                    #pragma unroll
                    for (int r = 0; r < 4; ++r) {
                        int li = wr * 64 + m * 16 + lg * 4 + r;
                        float a = 0.f;
                        #pragma unroll
                        for (int n = 0; n < 4; ++n) {
                            int lj = wc * 64 + n * 16 + l16;
                            float e = EXP2(acc[m][n][r]);
                            a += (li == dBase + lj) ? 0.f : e;
                        }
                        rs[m][r] += a;
                    }
            } else {
                float cs[4] = {0.f, 0.f, 0.f, 0.f};
                #pragma unroll
                for (int m = 0; m < 4; ++m)
                    #pragma unroll
                    for (int r = 0; r < 4; ++r) {
                        float a = 0.f;
                        #pragma unroll
                        for (int n = 0; n < 4; ++n) {
                            float e = EXP2(acc[m][n][r]);
                            a += e;
                            cs[n] += e;
                        }
                        rs[m][r] += a;
                    }
                // column flush: reduce over the 4 lg row-groups of this wave
                #pragma unroll
                for (int n = 0; n < 4; ++n) {
                    float v = cs[n];
                    v += __shfl_xor(v, 16);
                    v += __shfl_xor(v, 32);
                    if (lg == 0)
                        atomicAdd(&rowsum[jt * 128 + wc * 64 + n * 16 + l16], v);
                }
            }
        }
    }

    // row sums -> reduce across 16 column-lanes, one atomic/row
    #pragma unroll
    for (int m = 0; m < 4; ++m)
        #pragma unroll
        for (int r = 0; r < 4; ++r) {
            float v = rs[m][r];
            v += __shfl_xor(v, 1);
            v += __shfl_xor(v, 2);
            v += __shfl_xor(v, 4);
            v += __shfl_xor(v, 8);
            if (l16 == 0)
                atomicAdd(&rowsum[ti * 256 + wr * 64 + m * 16 + lg * 4 + r], v);
        }
}

// ---------- kernel 3: loss mean from rowsum + posparts (R21-verbatim) ----------
__global__ void k_loss_reduce(const float* __restrict__ rowsum,
                              const float* __restrict__ posparts,
                              float* __restrict__ out) {
    const int tid = threadIdx.x + blockIdx.x * 256;   // 64 blocks x 256 = 16384
    float part = logf(rowsum[tid]);
    if (blockIdx.x == 0) {
        float pp = 0.f;
        for (int i = threadIdx.x; i < N2 / 4; i += 256) pp += posparts[i];
        part -= LN2 * pp;
    }
    __shared__ float sm[4];
    #pragma unroll
    for (int m = 1; m < 64; m <<= 1) part += __shfl_xor(part, m);
    if ((threadIdx.x & 63) == 0) sm[threadIdx.x >> 6] = part;
    __syncthreads();
    if (threadIdx.x == 0)
        atomicAdd(out, (sm[0] + sm[1] + sm[2] + sm[3]) * (1.0f / (float)N2));
}

extern "C" void kernel_launch(void* const* d_in, const int* in_sizes, int n_in,
                              void* d_out, int out_size, void* d_ws, size_t ws_size,
                              hipStream_t stream) {
    const float* z = (const float*)d_in[0];
    float* out = (float*)d_out;

    unsigned short* zn = (unsigned short*)d_ws;                       // 4 MiB
    float* rowsum   = (float*)((char*)d_ws + (size_t)N2 * D * 2);     // 64 KiB
    float* posparts = rowsum + N2;                                    // 16 KiB

    k_norm<<<N2 / 4, 256, 0, stream>>>(z, zn, rowsum, posparts, out);
    dim3 grid(8, 64);                                                 // s-chunks x stripes
    k_sim<<<grid, 512, 0, stream>>>(zn, rowsum);
    k_loss_reduce<<<64, 256, 0, stream>>>(rowsum, posparts, out);
}

// Round 25
// 62.436 us; speedup vs baseline: 3.2589x; 1.1987x over previous
//
#include <hip/hip_runtime.h>
#include <hip/hip_bf16.h>

#define N2 16384
#define D  128
#define PANEL 32768                       // bytes per 128x128 bf16 panel
#define SQC1 1.69864360258810896f         // sqrt(2*log2(e)), folded into zn
#define LN2  0.69314718055994530942f

typedef __bf16 bf16x8 __attribute__((ext_vector_type(8)));
typedef float  f32x4  __attribute__((ext_vector_type(4)));

#if __has_builtin(__builtin_amdgcn_exp2f)
#define EXP2(x) __builtin_amdgcn_exp2f(x)
#else
#define EXP2(x) exp2f(x)
#endif

__device__ __forceinline__ unsigned short f2bf(float f) {
    union { float f; unsigned u; } v; v.f = f;
    unsigned r = v.u + 0x7fffu + ((v.u >> 16) & 1u);
    return (unsigned short)(r >> 16);
}

// stage one 32KB panel global->LDS via global_load_lds width=16.
// LDS dest linear; XOR swizzle on the GLOBAL source (involution); reads
// use byte ^ ((row&7)<<4). (rule #21)
__device__ __forceinline__ void stage_panel(const char* __restrict__ g,
                                            char* lds, int tid) {
    const int wid = tid >> 6, lane = tid & 63;
    #pragma unroll
    for (int i = 0; i < 8; ++i) {
        int off = (wid << 13) + (i << 10) + (lane << 4);
        int src = off ^ (((off >> 8) & 7) << 4);
        __builtin_amdgcn_global_load_lds(
            (const __attribute__((address_space(1))) unsigned*)(g + src),
            (__attribute__((address_space(3))) unsigned*)(lds + (wid << 13) + (i << 10)),
            16, 0, 0);
    }
}

// ---------- kernel 1: L2-normalize -> bf16 sqrt(C1)*zn; pos-dot in fp32 ----------
// Block handles rows 4b..4b+3; partner row r^1 is always in-block (wid^1).
// Normalized fp32 values exchanged via LDS -> per-block pos partial written
// unconditionally to posparts[bid]. Also zeroes rowsum slices and out.
__global__ void k_norm(const float* __restrict__ z, unsigned short* __restrict__ zn,
                       float* __restrict__ rowsum, float* __restrict__ posparts,
                       float* __restrict__ out) {
    __shared__ float xs[4][64][2];        // 2KB: normalized fp32 exchange
    __shared__ float ps[4];
    if (blockIdx.x < 64) rowsum[blockIdx.x * 256 + threadIdx.x] = 0.f;
    if (blockIdx.x == 64 && threadIdx.x == 0) out[0] = 0.f;
    int wid  = threadIdx.x >> 6, lane = threadIdx.x & 63;
    int row  = blockIdx.x * 4 + wid;
    const float2 v = ((const float2*)(z + (size_t)row * D))[lane];
    float ss = v.x * v.x + v.y * v.y;
    #pragma unroll
    for (int m = 1; m < 64; m <<= 1) ss += __shfl_xor(ss, m);
    float inv = SQC1 / fmaxf(sqrtf(ss), 1e-12f);
    float nx = v.x * inv, ny = v.y * inv;
    ushort2 o; o.x = f2bf(nx); o.y = f2bf(ny);
    ((ushort2*)(zn + (size_t)row * D))[lane] = o;

    // pos-dot with partner row (r^1 = wid^1 in this block), fp32
    xs[wid][lane][0] = nx; xs[wid][lane][1] = ny;
    __syncthreads();
    float d = nx * xs[wid ^ 1][lane][0] + ny * xs[wid ^ 1][lane][1];
    #pragma unroll
    for (int m = 1; m < 64; m <<= 1) d += __shfl_xor(d, m);
    if (lane == 0) ps[wid] = d;
    __syncthreads();
    if (threadIdx.x == 0)
        posparts[blockIdx.x] = ps[0] + ps[1] + ps[2] + ps[3];   // sum of folded dots
}

// ---------- kernel 2: symmetric fused sim GEMM (51.9us-verified structure) ----------
// block (c, ti): s in [16c, 16c+16) (+s=64 for c==3, ti<64). jt=(ti+s)&127.
// A(ti) in regs (staged once); B panels double-buffered in 2x32KB; vmcnt(8)
// counted prefetch; 2 barriers/tile; exp epilogue with row sums in regs and
// symmetric col sums via atomics. This structure is a verified plateau:
// 19 variants (occupancy/barriers/dtype/MFMA-shape/tile/atomics) all >= it.
__global__ __launch_bounds__(256, 2)
void k_sim(const unsigned short* __restrict__ zn, float* __restrict__ rowsum) {
    __shared__ unsigned short ls[2][PANEL / 2];
    char* ls0 = (char*)&ls[0][0];
    char* ls1 = (char*)&ls[1][0];

    const int tileI = blockIdx.y;
    const int sBase = blockIdx.x * 16;
    const int nt = (blockIdx.x == 3 && tileI < 64) ? 17 : 16;
    const int tid  = threadIdx.x;
    const int lane = tid & 63, wid = tid >> 6;
    const int wr = wid >> 1, wc = wid & 1;          // 2x2 wave grid, 64x64 each
    const int l16 = lane & 15, lg = lane >> 4;
    const char* znb = (const char*)zn;
    const f32x4 ZERO = {0.f, 0.f, 0.f, 0.f};

    // prologue: stage A(ti) -> ls0, B(s=sBase) -> ls1
    stage_panel(znb + (size_t)tileI * PANEL, ls0, tid);
    stage_panel(znb + (size_t)((tileI + sBase) & 127) * PANEL, ls1, tid);
    asm volatile("s_waitcnt vmcnt(8)" ::: "memory");   // A landed
    __builtin_amdgcn_s_barrier();

    // A fragments -> registers (reused for all tiles)
    bf16x8 af[4][4];                                   // [kk][m]
    #pragma unroll
    for (int kk = 0; kk < 4; ++kk)
        #pragma unroll
        for (int m = 0; m < 4; ++m) {
            int row = wr * 64 + m * 16 + l16;
            int d = row * 256 + kk * 64 + lg * 16;
            af[kk][m] = *(const bf16x8*)(ls0 + (d ^ ((row & 7) << 4)));
        }
    asm volatile("s_waitcnt lgkmcnt(0)" ::: "memory");
    __builtin_amdgcn_s_barrier();                      // ls0 now reusable

    float rs[4][4];
    #pragma unroll
    for (int m = 0; m < 4; ++m)
        #pragma unroll
        for (int r = 0; r < 4; ++r) rs[m][r] = 0.f;

    for (int t = 0; t < nt; ++t) {
        const int s  = sBase + t;
        const int jt = (tileI + s) & 127;
        char* rbuf = (t & 1) ? ls0 : ls1;              // B(s)
        char* sbuf = (t & 1) ? ls1 : ls0;              // B(s+1) dest
        if (t < nt - 1) {
            stage_panel(znb + (size_t)((tileI + s + 1) & 127) * PANEL, sbuf, tid);
            asm volatile("s_waitcnt vmcnt(8)" ::: "memory");  // B(s) landed
        } else {
            asm volatile("s_waitcnt vmcnt(0)" ::: "memory");
        }
        __builtin_amdgcn_s_barrier();

        bf16x8 bfr[4][4];                              // [kk][n]
        #pragma unroll
        for (int kk = 0; kk < 4; ++kk)
            #pragma unroll
            for (int n = 0; n < 4; ++n) {
                int row = wc * 64 + n * 16 + l16;
                int d = row * 256 + kk * 64 + lg * 16;
                bfr[kk][n] = *(const bf16x8*)(rbuf + (d ^ ((row & 7) << 4)));
            }
        asm volatile("s_waitcnt lgkmcnt(0)" ::: "memory");
        __builtin_amdgcn_s_barrier();                  // rbuf free for next stage

        f32x4 acc[4][4];
        #pragma unroll
        for (int m = 0; m < 4; ++m)
            #pragma unroll
            for (int n = 0; n < 4; ++n)
                acc[m][n] = __builtin_amdgcn_mfma_f32_16x16x32_bf16(af[0][m], bfr[0][n], ZERO, 0, 0, 0);
        #pragma unroll
        for (int kk = 1; kk < 4; ++kk)
            #pragma unroll
            for (int m = 0; m < 4; ++m)
                #pragma unroll
                for (int n = 0; n < 4; ++n)
                    acc[m][n] = __builtin_amdgcn_mfma_f32_16x16x32_bf16(af[kk][m], bfr[kk][n], acc[m][n], 0, 0, 0);

        // epilogue: e = exp2(acc) = exp(sim); rows accumulate in regs,
        // cols flushed per tile (jt changes every tile).
        if (s == 0) {
            // diagonal tile: mask self-sim, row sums only
            #pragma unroll
            for (int m = 0; m < 4; ++m)
                #pragma unroll
                for (int r = 0; r < 4; ++r) {
                    int li = wr * 64 + m * 16 + lg * 4 + r;
                    float a = 0.f;
                    #pragma unroll
                    for (int n = 0; n < 4; ++n) {
                        int lj = wc * 64 + n * 16 + l16;
                        float e = EXP2(acc[m][n][r]);
                        a += (li == lj) ? 0.f : e;
                    }
                    rs[m][r] += a;
                }
        } else {
            float cs[4] = {0.f, 0.f, 0.f, 0.f};
            #pragma unroll
            for (int m = 0; m < 4; ++m)
                #pragma unroll
                for (int r = 0; r < 4; ++r) {
                    float a = 0.f;
                    #pragma unroll
                    for (int n = 0; n < 4; ++n) {
                        float e = EXP2(acc[m][n][r]);
                        a += e;
                        cs[n] += e;
                    }
                    rs[m][r] += a;
                }
            // column flush: reduce over the 4 lg row-groups of this wave
            #pragma unroll
            for (int n = 0; n < 4; ++n) {
                float v = cs[n];
                v += __shfl_xor(v, 16);
                v += __shfl_xor(v, 32);
                if (lg == 0)
                    atomicAdd(&rowsum[jt * 128 + wc * 64 + n * 16 + l16], v);
            }
        }
    }

    // final: row sums -> reduce across 16 column-lanes, one atomic/row
    #pragma unroll
    for (int m = 0; m < 4; ++m)
        #pragma unroll
        for (int r = 0; r < 4; ++r) {
            float v = rs[m][r];
            v += __shfl_xor(v, 1);
            v += __shfl_xor(v, 2);
            v += __shfl_xor(v, 4);
            v += __shfl_xor(v, 8);
            if (l16 == 0)
                atomicAdd(&rowsum[tileI * 128 + wr * 64 + m * 16 + lg * 4 + r], v);
        }
}

// ---------- kernel 3: loss mean from rowsum + posparts only ----------
// mean loss = (1/N2) * [ sum_i ln(rowsum_i) - ln2 * sum_b posparts_b ]
__global__ void k_loss_reduce(const float* __restrict__ rowsum,
                              const float* __restrict__ posparts,
                              float* __restrict__ out) {
    const int tid = threadIdx.x + blockIdx.x * 256;   // 64 blocks x 256 = 16384
    float part = logf(rowsum[tid]);
    if (blockIdx.x == 0) {                            // fold pos partials (4096)
        float pp = 0.f;
        for (int i = threadIdx.x; i < N2 / 4; i += 256) pp += posparts[i];
        part -= LN2 * pp;
    }
    __shared__ float sm[4];
    #pragma unroll
    for (int m = 1; m < 64; m <<= 1) part += __shfl_xor(part, m);
    if ((threadIdx.x & 63) == 0) sm[threadIdx.x >> 6] = part;
    __syncthreads();
    if (threadIdx.x == 0)
        atomicAdd(out, (sm[0] + sm[1] + sm[2] + sm[3]) * (1.0f / (float)N2));
}

extern "C" void kernel_launch(void* const* d_in, const int* in_sizes, int n_in,
                              void* d_out, int out_size, void* d_ws, size_t ws_size,
                              hipStream_t stream) {
    const float* z = (const float*)d_in[0];
    float* out = (float*)d_out;

    unsigned short* zn = (unsigned short*)d_ws;                       // 4 MiB
    float* rowsum   = (float*)((char*)d_ws + (size_t)N2 * D * 2);     // 64 KiB
    float* posparts = rowsum + N2;                                    // 16 KiB

    k_norm<<<N2 / 4, 256, 0, stream>>>(z, zn, rowsum, posparts, out);
    dim3 grid(4, 128);                                                // s-chunks x i-tiles
    k_sim<<<grid, 256, 0, stream>>>(zn, rowsum);
    k_loss_reduce<<<64, 256, 0, stream>>>(rowsum, posparts, out);
}